// Round 2
// baseline (26461.005 us; speedup 1.0000x reference)
//
#include <hip/hip_runtime.h>
#include <hip/hip_bf16.h>

// Problem constants (b=4, n=4, c=256, h=w=64, k=128, out_c=256) — all tensors fp32
#define B   4
#define NN  4
#define C   256
#define HH  64
#define WW  64
#define L   4096      // H*W
#define NL  16384     // NN*L
#define K   128
#define OC  256
#define IC2 512       // 2*C
#define EPSV 1e-6f

typedef __hip_bfloat16 bf16;

// ---------------- init: mu[b][c][k] = broadcast mu0 --------------------------------------
__global__ void k_init(const float* __restrict__ mu0, float* __restrict__ mu) {
    int i = blockIdx.x * 256 + threadIdx.x;
    mu[i] = mu0[i & (C * K - 1)];
}

// ---------------- EM step A: z[b][l][k] = softmax_k( sum_c x[b][c][l] * mu[b][c][k] ) -------
// One wave per l; lane holds k=lane and k=lane+64.
__global__ void k_z(const float* __restrict__ x, const float* __restrict__ mu,
                    float* __restrict__ z) {
    int wave = threadIdx.x >> 6;
    int lane = threadIdx.x & 63;
    int id = blockIdx.x * 4 + wave;        // b*L + l
    int b = id >> 12;
    int l = id & 4095;
    const float* xc = x + (size_t)b * C * L + l;
    const float* mb = mu + (size_t)b * C * K;
    float a0 = 0.f, a1 = 0.f;
    for (int c = 0; c < C; c++) {
        float xv = xc[(size_t)c * L];               // broadcast across lanes
        a0 += xv * mb[c * K + lane];                // coalesced
        a1 += xv * mb[c * K + lane + 64];
    }
    float m = fmaxf(a0, a1);
    for (int o = 32; o > 0; o >>= 1) m = fmaxf(m, __shfl_xor(m, o, 64));
    float e0 = __expf(a0 - m), e1 = __expf(a1 - m);
    float s = e0 + e1;
    for (int o = 32; o > 0; o >>= 1) s += __shfl_xor(s, o, 64);
    float inv = 1.f / s;
    float* zr = z + (size_t)id * K;
    zr[lane]      = e0 * inv;
    zr[lane + 64] = e1 * inv;
}

// ---------------- EM step B: mu_t[b][c][k] = sum_l x[b][c][l] * z[b][l][k] ------------------
// (column-sum normalization of z dropped: per-k scale is removed by the c-l2norm)
__global__ void k_mu(const float* __restrict__ x, const float* __restrict__ z,
                     float* __restrict__ mu_t) {
    int k    = threadIdx.x & 127;
    int csub = threadIdx.x >> 7;           // 0..1
    int b  = blockIdx.x >> 6;
    int c0 = (blockIdx.x & 63) * 4 + csub * 2;
    const float* zb = z + (size_t)b * L * K + k;
    const float* xb = x + (size_t)b * C * L;
    float a0 = 0.f, a1 = 0.f;
    for (int l = 0; l < L; l++) {
        float zv = zb[(size_t)l * K];                       // coalesced over k
        a0 += xb[(size_t)c0 * L + l] * zv;                  // broadcast
        a1 += xb[(size_t)(c0 + 1) * L + l] * zv;
    }
    mu_t[((size_t)b * C + c0)     * K + k] = a0;
    mu_t[((size_t)b * C + c0 + 1) * K + k] = a1;
}

// ---------------- l2norm over c: mu[b][c][k] = mu_t / (eps + ||mu_t||_c) --------------------
__global__ void k_norm(const float* __restrict__ mu_t, float* __restrict__ mu) {
    int b = blockIdx.x >> 7, k = blockIdx.x & 127, lane = threadIdx.x;
    float v[4]; float s = 0.f;
    #pragma unroll
    for (int j = 0; j < 4; j++) {
        v[j] = mu_t[((size_t)b * C + lane + 64 * j) * K + k];
        s += v[j] * v[j];
    }
    for (int o = 32; o > 0; o >>= 1) s += __shfl_xor(s, o, 64);
    float r = 1.f / (EPSV + sqrtf(s));
    #pragma unroll
    for (int j = 0; j < 4; j++)
        mu[((size_t)b * C + lane + 64 * j) * K + k] = v[j] * r;
}

// ---------------- q_z[b][l'][k] = softmax_k( sum_c q[b][c][l'] * mu[b][c][k] ) --------------
// l' = nidx*L + p ; q[b][c][l'] = querys[(b*NN+nidx)][c][p]
__global__ void k_qz(const float* __restrict__ qy, const float* __restrict__ mu,
                     float* __restrict__ qz) {
    int wave = threadIdx.x >> 6;
    int lane = threadIdx.x & 63;
    int id = blockIdx.x * 4 + wave;        // b*NL + l'
    int b  = id >> 14;
    int lp = id & 16383;
    int nidx = lp >> 12, p = lp & 4095;
    const float* qc = qy + ((size_t)(b * NN + nidx) * C) * L + p;
    const float* mb = mu + (size_t)b * C * K;
    float a0 = 0.f, a1 = 0.f;
    for (int c = 0; c < C; c++) {
        float qv = qc[(size_t)c * L];
        a0 += qv * mb[c * K + lane];
        a1 += qv * mb[c * K + lane + 64];
    }
    float m = fmaxf(a0, a1);
    for (int o = 32; o > 0; o >>= 1) m = fmaxf(m, __shfl_xor(m, o, 64));
    float e0 = __expf(a0 - m), e1 = __expf(a1 - m);
    float s = e0 + e1;
    for (int o = 32; o > 0; o >>= 1) s += __shfl_xor(s, o, 64);
    float inv = 1.f / s;
    float* zr = qz + (size_t)id * K;
    zr[lane]      = e0 * inv;
    zr[lane + 64] = e1 * inv;
}

// ---------------- rec[b][c][l'] = sum_k mu[b][c][k] * qz[b][l'][k]  (bf16 scratch) ----------
__global__ void k_rec(const float* __restrict__ mu, const float* __restrict__ qz,
                      bf16* __restrict__ rec) {
    __shared__ float qt[64][K + 1];        // +1 pad: conflict-free
    int b  = blockIdx.x >> 8;
    int l0 = (blockIdx.x & 255) * 64;
    int t = threadIdx.x;
    for (int idx = t; idx < 64 * K; idx += 256) {
        int r = idx >> 7, col = idx & 127;
        qt[r][col] = qz[((size_t)b * NL + l0 + r) * K + col];
    }
    __syncthreads();
    int lane = t & 63, csub = t >> 6;
    const float* mb = mu + (size_t)b * C * K;
    for (int cp = 0; cp < 16; cp++) {
        int c = cp * 16 + csub * 4;
        float a0 = 0.f, a1 = 0.f, a2 = 0.f, a3 = 0.f;
        for (int k = 0; k < K; k++) {
            float qv = qt[lane][k];
            a0 += mb[(c + 0) * K + k] * qv;   // wave-uniform loads
            a1 += mb[(c + 1) * K + k] * qv;
            a2 += mb[(c + 2) * K + k] * qv;
            a3 += mb[(c + 3) * K + k] * qv;
        }
        size_t o = ((size_t)b * C + c) * NL + l0 + lane;
        rec[o]          = __float2bfloat16(a0);
        rec[o + NL]     = __float2bfloat16(a1);
        rec[o + 2 * NL] = __float2bfloat16(a2);
        rec[o + 3 * NL] = __float2bfloat16(a3);
    }
}

// ---------------- direct 3x3 SAME conv: in = [querys(256ch) | rec(256ch)], fp32 out ---------
__global__ void __launch_bounds__(256) k_conv(const float* __restrict__ qy,
                                              const bf16* __restrict__ rec,
                                              const float* __restrict__ cw,
                                              const float* __restrict__ cb,
                                              float* __restrict__ out) {
    int t = threadIdx.x;
    int xx0  = t & 63;        // pixel x (64 lanes -> full row, coalesced)
    int osub = t >> 6;        // wave-uniform oc
    int oc  = blockIdx.x * 4 + osub;
    int y   = blockIdx.y;
    int img = blockIdx.z;
    int b = img >> 2, nidx = img & 3;
    float acc = cb[oc];
    const float* wrow = cw + (size_t)oc * IC2 * 9;
    for (int ic = 0; ic < C; ic++) {
        const float* base = qy + ((size_t)img * C + ic) * L;
        const float* w9 = wrow + ic * 9;
        #pragma unroll
        for (int dy = -1; dy <= 1; dy++) {
            int yy = y + dy;
            if (yy < 0 || yy >= HH) continue;       // wave-uniform branch
            const float* row = base + yy * WW;
            #pragma unroll
            for (int dx = -1; dx <= 1; dx++) {
                int xx = xx0 + dx;
                float v = (xx >= 0 && xx < WW) ? row[xx] : 0.f;
                acc += v * w9[(dy + 1) * 3 + (dx + 1)];
            }
        }
    }
    for (int ic = 0; ic < C; ic++) {
        const bf16* base = rec + ((size_t)b * C + ic) * NL + (size_t)nidx * L;
        const float* w9 = wrow + (C + ic) * 9;
        #pragma unroll
        for (int dy = -1; dy <= 1; dy++) {
            int yy = y + dy;
            if (yy < 0 || yy >= HH) continue;
            const bf16* row = base + yy * WW;
            #pragma unroll
            for (int dx = -1; dx <= 1; dx++) {
                int xx = xx0 + dx;
                float v = (xx >= 0 && xx < WW) ? __bfloat162float(row[xx]) : 0.f;
                acc += v * w9[(dy + 1) * 3 + (dx + 1)];
            }
        }
    }
    out[((size_t)img * OC + oc) * L + y * WW + xx0] = acc;
}

// ---------------- mu (fp32 ws) -> fp32 tail of d_out ----------------------------------------
__global__ void k_muout(const float* __restrict__ mu, float* __restrict__ out) {
    int i = blockIdx.x * 256 + threadIdx.x;
    out[(size_t)16777216 + i] = mu[i];
}

extern "C" void kernel_launch(void* const* d_in, const int* in_sizes, int n_in,
                              void* d_out, int out_size, void* d_ws, size_t ws_size,
                              hipStream_t stream) {
    const float* x   = (const float*)d_in[0];   // [4][256][4096]
    const float* qy  = (const float*)d_in[1];   // [16][256][4096]
    const float* mu0 = (const float*)d_in[2];   // [256][128]
    const float* cw  = (const float*)d_in[3];   // [256][512][3][3]
    const float* cb  = (const float*)d_in[4];   // [256]
    float* out = (float*)d_out;                 // 16,777,216 conv out + 131,072 mu (fp32)

    // workspace (bytes): mu 512K | mu_t 512K | qz 32M | rec(bf16) 32M  (~65 MB)
    float* mu   = (float*)d_ws;
    float* mu_t = mu + 131072;
    float* qz   = mu_t + 131072;              // B*NL*K fp32 (EM z uses first quarter)
    bf16*  rec  = (bf16*)(qz + 8388608);

    k_init<<<512, 256, 0, stream>>>(mu0, mu);

    for (int it = 0; it < 5; it++) {
        k_z<<<B * L / 4, 256, 0, stream>>>(x, mu, qz);
        k_mu<<<B * 64, 256, 0, stream>>>(x, qz, mu_t);
        k_norm<<<B * K, 64, 0, stream>>>(mu_t, mu);
    }

    k_qz<<<B * NL / 4, 256, 0, stream>>>(qy, mu, qz);
    k_rec<<<B * 256, 256, 0, stream>>>(mu, qz, rec);
    k_conv<<<dim3(64, 64, 16), 256, 0, stream>>>(qy, rec, cw, cb, out);
    k_muout<<<512, 256, 0, stream>>>(mu, out);
}

// Round 3
// 2288.651 us; speedup vs baseline: 11.5618x; 11.5618x over previous
//
#include <hip/hip_runtime.h>
#include <hip/hip_bf16.h>

// Problem constants (b=4, n=4, c=256, h=w=64, k=128, out_c=256) — all tensors fp32
#define B   4
#define NN  4
#define C   256
#define HH  64
#define WW  64
#define L   4096      // H*W
#define NL  16384     // NN*L
#define K   128
#define OC  256
#define IC2 512       // 2*C
#define EPSV 1e-6f
#define PW  66        // padded width/height
#define PA  4356      // 66*66

typedef __hip_bfloat16 bf16;
typedef __attribute__((ext_vector_type(8))) __bf16 bf16x8;
typedef __attribute__((ext_vector_type(4))) float f32x4;

#define AS1(p) ((const __attribute__((address_space(1))) void*)(p))
#define AS3(p) ((__attribute__((address_space(3))) void*)(p))

__device__ __forceinline__ float b2f(bf16 v){ return __bfloat162float(v); }

// ---------------- init: mu[b][c][k] = broadcast mu0 -----------------------------------------
__global__ void k_init(const float* __restrict__ mu0, float* __restrict__ mu) {
    int i = blockIdx.x * 256 + threadIdx.x;
    mu[i] = mu0[i & (C * K - 1)];
}

// ---------------- EM step A: z[b][l][k] = softmax_k( sum_c x[b][c][l] * mu[b][c][k] ) -------
__global__ void k_z(const float* __restrict__ x, const float* __restrict__ mu,
                    float* __restrict__ z) {
    int wave = threadIdx.x >> 6;
    int lane = threadIdx.x & 63;
    int id = blockIdx.x * 4 + wave;        // b*L + l
    int b = id >> 12;
    int l = id & 4095;
    const float* xc = x + (size_t)b * C * L + l;
    const float* mb = mu + (size_t)b * C * K;
    float a0 = 0.f, a1 = 0.f;
    for (int c = 0; c < C; c++) {
        float xv = xc[(size_t)c * L];
        a0 += xv * mb[c * K + lane];
        a1 += xv * mb[c * K + lane + 64];
    }
    float m = fmaxf(a0, a1);
    for (int o = 32; o > 0; o >>= 1) m = fmaxf(m, __shfl_xor(m, o, 64));
    float e0 = __expf(a0 - m), e1 = __expf(a1 - m);
    float s = e0 + e1;
    for (int o = 32; o > 0; o >>= 1) s += __shfl_xor(s, o, 64);
    float inv = 1.f / s;
    float* zr = z + (size_t)id * K;
    zr[lane]      = e0 * inv;
    zr[lane + 64] = e1 * inv;
}

// ---------------- EM step B: mu_t[b][c][k] = sum_l x[b][c][l] * z[b][l][k] ------------------
__global__ void k_mu(const float* __restrict__ x, const float* __restrict__ z,
                     float* __restrict__ mu_t) {
    int k    = threadIdx.x & 127;
    int csub = threadIdx.x >> 7;
    int b  = blockIdx.x >> 6;
    int c0 = (blockIdx.x & 63) * 4 + csub * 2;
    const float* zb = z + (size_t)b * L * K + k;
    const float* xb = x + (size_t)b * C * L;
    float a0 = 0.f, a1 = 0.f;
    for (int l = 0; l < L; l++) {
        float zv = zb[(size_t)l * K];
        a0 += xb[(size_t)c0 * L + l] * zv;
        a1 += xb[(size_t)(c0 + 1) * L + l] * zv;
    }
    mu_t[((size_t)b * C + c0)     * K + k] = a0;
    mu_t[((size_t)b * C + c0 + 1) * K + k] = a1;
}

// ---------------- l2norm over c ------------------------------------------------------------
__global__ void k_norm(const float* __restrict__ mu_t, float* __restrict__ mu) {
    int b = blockIdx.x >> 7, k = blockIdx.x & 127, lane = threadIdx.x;
    float v[4]; float s = 0.f;
    #pragma unroll
    for (int j = 0; j < 4; j++) {
        v[j] = mu_t[((size_t)b * C + lane + 64 * j) * K + k];
        s += v[j] * v[j];
    }
    for (int o = 32; o > 0; o >>= 1) s += __shfl_xor(s, o, 64);
    float r = 1.f / (EPSV + sqrtf(s));
    #pragma unroll
    for (int j = 0; j < 4; j++)
        mu[((size_t)b * C + lane + 64 * j) * K + k] = v[j] * r;
}

// ---------------- q_z (bf16 out) -----------------------------------------------------------
__global__ void k_qz(const float* __restrict__ qy, const float* __restrict__ mu,
                     bf16* __restrict__ qz) {
    int wave = threadIdx.x >> 6;
    int lane = threadIdx.x & 63;
    int id = blockIdx.x * 4 + wave;        // b*NL + l'
    int b  = id >> 14;
    int lp = id & 16383;
    int nidx = lp >> 12, p = lp & 4095;
    const float* qc = qy + ((size_t)(b * NN + nidx) * C) * L + p;
    const float* mb = mu + (size_t)b * C * K;
    float a0 = 0.f, a1 = 0.f;
    for (int c = 0; c < C; c++) {
        float qv = qc[(size_t)c * L];
        a0 += qv * mb[c * K + lane];
        a1 += qv * mb[c * K + lane + 64];
    }
    float m = fmaxf(a0, a1);
    for (int o = 32; o > 0; o >>= 1) m = fmaxf(m, __shfl_xor(m, o, 64));
    float e0 = __expf(a0 - m), e1 = __expf(a1 - m);
    float s = e0 + e1;
    for (int o = 32; o > 0; o >>= 1) s += __shfl_xor(s, o, 64);
    float inv = 1.f / s;
    bf16* zr = qz + (size_t)id * K;
    zr[lane]      = __float2bfloat16(e0 * inv);
    zr[lane + 64] = __float2bfloat16(e1 * inv);
}

// ---------------- zero padded buffer P2 ----------------------------------------------------
__global__ void k_zerop(uint4* __restrict__ p) {
    size_t n = (size_t)16 * PA * 512 * 2 / 16;   // 4,460,544
    for (size_t i = blockIdx.x * 256 + threadIdx.x; i < n; i += (size_t)gridDim.x * 256)
        p[i] = uint4{0, 0, 0, 0};
}

// ---------------- weights: cw fp32 [oc][ic][3][3] -> Wb bf16 [r][oc][ic] --------------------
__global__ void k_wprep(const float* __restrict__ cw, bf16* __restrict__ wb) {
    int idx = blockIdx.x * 256 + threadIdx.x;     // over 9*256*512
    if (idx >= 9 * OC * IC2) return;
    int r  = idx / (OC * IC2);
    int oc = (idx / IC2) & 255;
    int ic = idx & 511;
    wb[idx] = __float2bfloat16(cw[((size_t)oc * IC2 + ic) * 9 + r]);
}

// ---------------- qy fp32 [img][ch][px] -> P2 bf16 [img][py][px][ch] (interior) -------------
__global__ void k_xpose(const float* __restrict__ qy, bf16* __restrict__ P2) {
    __shared__ float ld[64][65];
    int y = blockIdx.x, ch0 = blockIdx.y * 64, img = blockIdx.z;
    int t = threadIdx.x;
    #pragma unroll
    for (int i = 0; i < 16; i++) {
        int idx = t + i * 256;
        int ch_l = idx >> 6, x_l = idx & 63;
        ld[ch_l][x_l] = qy[((size_t)img * C + ch0 + ch_l) * L + y * WW + x_l];
    }
    __syncthreads();
    #pragma unroll
    for (int i = 0; i < 16; i++) {
        int idx = t + i * 256;
        int x_l = idx >> 6, ch_l = idx & 63;
        P2[((size_t)img * PA + (size_t)(y + 1) * PW + x_l + 1) * 512 + ch0 + ch_l] =
            __float2bfloat16(ld[ch_l][x_l]);
    }
}

// ---------------- rec -> P2 channels 256..511 (interior): rec = sum_k mu[c][k]*qz[l'][k] ----
__global__ void k_rec(const float* __restrict__ mu, const bf16* __restrict__ qz,
                      bf16* __restrict__ P2) {
    __shared__ float qt[64][K + 1];
    int b    = blockIdx.x >> 8;
    int tile = blockIdx.x & 255;
    int l0   = tile * 64;
    int nidx = tile >> 6;
    int y    = tile & 63;
    int img  = b * NN + nidx;
    int t = threadIdx.x;
    for (int idx = t; idx < 64 * K; idx += 256) {
        int r = idx >> 7, col = idx & 127;
        qt[r][col] = b2f(qz[((size_t)b * NL + l0 + r) * K + col]);
    }
    __syncthreads();
    int lane = t & 63, csub = t >> 6;
    const float* mb = mu + (size_t)b * C * K;
    size_t pbase = ((size_t)img * PA + (size_t)(y + 1) * PW + lane + 1) * 512 + 256;
    for (int cp = 0; cp < 16; cp++) {
        int c = cp * 16 + csub * 4;
        float a0 = 0.f, a1 = 0.f, a2 = 0.f, a3 = 0.f;
        for (int k = 0; k < K; k++) {
            float qv = qt[lane][k];
            a0 += mb[(c + 0) * K + k] * qv;
            a1 += mb[(c + 1) * K + k] * qv;
            a2 += mb[(c + 2) * K + k] * qv;
            a3 += mb[(c + 3) * K + k] * qv;
        }
        bf16 tmp[4] = {__float2bfloat16(a0), __float2bfloat16(a1),
                       __float2bfloat16(a2), __float2bfloat16(a3)};
        *(uint2*)((char*)P2 + (pbase + c) * 2) = *(uint2*)tmp;
    }
}

// ---------------- MFMA implicit-GEMM conv: out[img][oc][px] = sum_{r,ic} Wb*P2 --------------
// Tile 128oc x 128px, BK=32, K = 9*512 = 4608. 4 waves, 4x4 16x16x32 frags each.
__global__ void __launch_bounds__(256) k_conv(const bf16* __restrict__ P2,
                                              const bf16* __restrict__ Wb,
                                              const float* __restrict__ cb,
                                              float* __restrict__ out) {
    __shared__ __align__(16) char smem[16384];    // A 8KB | B 8KB
    char* tA = smem;
    char* tB = smem + 8192;
    int t = threadIdx.x, wave = t >> 6, lane = t & 63;
    int m0  = blockIdx.x * 128;
    int y0  = blockIdx.y * 2;
    int img = blockIdx.z;

    // staging invariants: chunk = j*256+t -> row = j*64 + (t>>2), seg_stored = t&3
    int px0  = t >> 2;                 // 0..63
    int sseg = t & 3;
    int aseg = sseg ^ (px0 & 3);       // xor swizzle; (px0+64)&3 == px0&3
    int px1  = px0 + 64;
    size_t baseB0 = ((size_t)img * PA + (size_t)(y0 + (px0 >> 6)) * PW + (px0 & 63)) * 512 + aseg * 8;
    size_t baseB1 = ((size_t)img * PA + (size_t)(y0 + (px1 >> 6)) * PW + (px1 & 63)) * 512 + aseg * 8;
    size_t baseA0 = (size_t)(m0 + px0) * 512 + aseg * 8;
    size_t baseA1 = (size_t)(m0 + px1) * 512 + aseg * 8;
    char* ldsA0 = tA + wave * 1024;  char* ldsA1 = tA + 4096 + wave * 1024;
    char* ldsB0 = tB + wave * 1024;  char* ldsB1 = tB + 4096 + wave * 1024;

    // fragment read offsets (bytes), loop-invariant
    int wm = wave >> 1, wn = wave & 1;
    int aoff[4], boff[4];
    #pragma unroll
    for (int i = 0; i < 4; i++) {
        int rowA = wm * 64 + i * 16 + (lane & 15);
        aoff[i] = (rowA * 4 + ((lane >> 4) ^ (rowA & 3))) * 16;
        int rowB = wn * 64 + i * 16 + (lane & 15);
        boff[i] = (rowB * 4 + ((lane >> 4) ^ (rowB & 3))) * 16;
    }

    // acc init with bias: D row (oc) = (lane>>4)*4 + reg
    f32x4 acc[4][4];
    #pragma unroll
    for (int i = 0; i < 4; i++) {
        int oc = m0 + wm * 64 + i * 16 + (lane >> 4) * 4;
        #pragma unroll
        for (int r = 0; r < 4; r++) {
            float bv = cb[oc + r];
            #pragma unroll
            for (int j = 0; j < 4; j++) acc[i][j][r] = bv;
        }
    }

    for (int kk = 0; kk < 144; kk++) {
        int r   = kk >> 4;
        int ic0 = (kk & 15) << 5;
        size_t offB = (size_t)((r / 3) * PW + (r % 3)) * 512 + ic0;
        size_t offA = (size_t)r * (OC * IC2) + ic0;
        __syncthreads();
        __builtin_amdgcn_global_load_lds(AS1(Wb + baseA0 + offA), AS3(ldsA0), 16, 0, 0);
        __builtin_amdgcn_global_load_lds(AS1(Wb + baseA1 + offA), AS3(ldsA1), 16, 0, 0);
        __builtin_amdgcn_global_load_lds(AS1(P2 + baseB0 + offB), AS3(ldsB0), 16, 0, 0);
        __builtin_amdgcn_global_load_lds(AS1(P2 + baseB1 + offB), AS3(ldsB1), 16, 0, 0);
        __syncthreads();
        bf16x8 af[4], bfr[4];
        #pragma unroll
        for (int i = 0; i < 4; i++) af[i]  = *(bf16x8*)(tA + aoff[i]);
        #pragma unroll
        for (int j = 0; j < 4; j++) bfr[j] = *(bf16x8*)(tB + boff[j]);
        #pragma unroll
        for (int i = 0; i < 4; i++)
            #pragma unroll
            for (int j = 0; j < 4; j++)
                acc[i][j] = __builtin_amdgcn_mfma_f32_16x16x32_bf16(af[i], bfr[j], acc[i][j], 0, 0, 0);
    }

    // epilogue: D col (px) = lane&15, row (oc) = (lane>>4)*4 + reg
    int pxbase = blockIdx.y * 128 + wn * 64 + (lane & 15);
    #pragma unroll
    for (int i = 0; i < 4; i++) {
        int oc = m0 + wm * 64 + i * 16 + (lane >> 4) * 4;
        #pragma unroll
        for (int j = 0; j < 4; j++) {
            int px = pxbase + j * 16;
            #pragma unroll
            for (int r = 0; r < 4; r++)
                out[((size_t)img * OC + oc + r) * L + px] = acc[i][j][r];
        }
    }
}

// ---------------- mu (fp32 ws) -> fp32 tail of d_out ----------------------------------------
__global__ void k_muout(const float* __restrict__ mu, float* __restrict__ out) {
    int i = blockIdx.x * 256 + threadIdx.x;
    out[(size_t)16777216 + i] = mu[i];
}

extern "C" void kernel_launch(void* const* d_in, const int* in_sizes, int n_in,
                              void* d_out, int out_size, void* d_ws, size_t ws_size,
                              hipStream_t stream) {
    const float* x   = (const float*)d_in[0];   // [4][256][4096]
    const float* qy  = (const float*)d_in[1];   // [16][256][4096]
    const float* mu0 = (const float*)d_in[2];   // [256][128]
    const float* cw  = (const float*)d_in[3];   // [256][512][3][3]
    const float* cb  = (const float*)d_in[4];   // [256]
    float* out = (float*)d_out;                 // 16,777,216 conv + 131,072 mu (fp32)

    // workspace layout (bytes):
    //   mu   @ 0        (512 KB)
    //   mu_t @ 512 KB   (512 KB)
    //   Wb   @ 1 MB     (2.25 MB bf16 [9][256][512])
    //   z/qz @ 4 MB     (EM z fp32 8 MB, later qz bf16 16.78 MB — EM z dead by then)
    //   P2   @ 20971520 (71.37 MB bf16 [16][66*66][512])   total ~92.3 MB
    char* ws = (char*)d_ws;
    float* mu   = (float*)(ws);
    float* mu_t = (float*)(ws + 524288);
    bf16*  Wb   = (bf16*) (ws + 1048576);
    float* zf   = (float*)(ws + 4194304);
    bf16*  qzb  = (bf16*) (ws + 4194304);
    bf16*  P2   = (bf16*) (ws + 20971520);

    k_init<<<512, 256, 0, stream>>>(mu0, mu);
    for (int it = 0; it < 5; it++) {
        k_z<<<B * L / 4, 256, 0, stream>>>(x, mu, zf);
        k_mu<<<B * 64, 256, 0, stream>>>(x, zf, mu_t);
        k_norm<<<B * K, 64, 0, stream>>>(mu_t, mu);
    }

    k_qz<<<B * NL / 4, 256, 0, stream>>>(qy, mu, qzb);

    k_zerop<<<2048, 256, 0, stream>>>((uint4*)P2);
    k_wprep<<<(9 * OC * IC2 + 255) / 256, 256, 0, stream>>>(cw, Wb);
    k_xpose<<<dim3(64, 4, 16), 256, 0, stream>>>(qy, P2);
    k_rec<<<B * 256, 256, 0, stream>>>(mu, qzb, P2);

    k_conv<<<dim3(2, 32, 16), 256, 0, stream>>>(P2, Wb, cb, out);
    k_muout<<<512, 256, 0, stream>>>(mu, out);
}

// Round 4
// 514.496 us; speedup vs baseline: 51.4310x; 4.4483x over previous
//
#include <hip/hip_runtime.h>
#include <hip/hip_bf16.h>

// Problem constants (b=4, n=4, c=256, h=w=64, k=128, out_c=256) — all I/O fp32
#define B   4
#define NN  4
#define C   256
#define HH  64
#define WW  64
#define L   4096      // H*W
#define NL  16384     // NN*L
#define K   128
#define OC  256
#define IC2 512       // 2*C
#define EPSV 1e-6f
#define PW  66        // padded width/height
#define PA  4356      // 66*66

typedef __hip_bfloat16 bf16;
typedef __attribute__((ext_vector_type(8))) __bf16 bf16x8;
typedef __attribute__((ext_vector_type(4))) float f32x4;

#define AS1(p) ((const __attribute__((address_space(1))) void*)(p))
#define AS3(p) ((__attribute__((address_space(3))) void*)(p))

// ---------------- init: mu_f/mu_bf [b][k][c] from mu0 [c][k] --------------------------------
__global__ void k_init(const float* __restrict__ mu0, float* __restrict__ mu_f,
                       bf16* __restrict__ mub) {
    int i = blockIdx.x * 256 + threadIdx.x;        // over B*128*256
    int rem = i & 32767;
    int k = rem >> 8, c = rem & 255;
    float v = mu0[c * 128 + k];
    mu_f[i] = v;
    mub[i]  = __float2bfloat16(v);
}

// ---------------- x fp32 [b][c][l] -> x_bf [b][c][l] + xt [b][l][c] bf16 --------------------
__global__ void k_prepx(const float* __restrict__ x, bf16* __restrict__ xb,
                        bf16* __restrict__ xt) {
    __shared__ float ld[64][65];
    int lt = blockIdx.x, ct = blockIdx.y, b = blockIdx.z;
    int t = threadIdx.x;
    #pragma unroll
    for (int i = 0; i < 16; i++) {
        int idx = t + i * 256;
        int ch = idx >> 6, xl = idx & 63;
        size_t a = ((size_t)b * C + ct * 64 + ch) * L + lt * 64 + xl;
        float v = x[a];
        ld[ch][xl] = v;
        xb[a] = __float2bfloat16(v);
    }
    __syncthreads();
    #pragma unroll
    for (int i = 0; i < 16; i++) {
        int idx = t + i * 256;
        int xl = idx >> 6, ch = idx & 63;
        xt[((size_t)b * L + lt * 64 + xl) * 256 + ct * 64 + ch] = __float2bfloat16(ld[ch][xl]);
    }
}

// ---------------- qy fp32 [img][c][l] -> P2 interior ch<256 (bf16, ch-innermost) ------------
__global__ void k_prepq(const float* __restrict__ qy, bf16* __restrict__ P2) {
    __shared__ float ld[64][65];
    int y = blockIdx.x, ct = blockIdx.y, img = blockIdx.z;
    int t = threadIdx.x;
    #pragma unroll
    for (int i = 0; i < 16; i++) {
        int idx = t + i * 256;
        int ch = idx >> 6, xl = idx & 63;
        ld[ch][xl] = qy[((size_t)img * C + ct * 64 + ch) * L + y * WW + xl];
    }
    __syncthreads();
    #pragma unroll
    for (int i = 0; i < 16; i++) {
        int idx = t + i * 256;
        int xl = idx >> 6, ch = idx & 63;
        P2[((size_t)img * PA + (size_t)(y + 1) * PW + xl + 1) * 512 + ct * 64 + ch] =
            __float2bfloat16(ld[ch][xl]);
    }
}

// ---------------- zero only the P2 border pixels (all 512 ch) -------------------------------
__global__ void k_zborder(uint4* __restrict__ P2) {
    int pi = blockIdx.x, img = blockIdx.y, t = threadIdx.x;  // 64 threads, 64 uint4/pixel
    int y, x;
    if      (pi < 66)  { y = 0;        x = pi; }
    else if (pi < 132) { y = 65;       x = pi - 66; }
    else if (pi < 196) { y = pi - 131; x = 0; }
    else               { y = pi - 195; x = 65; }
    P2[((size_t)img * PA + (size_t)y * PW + x) * 64 + t] = uint4{0, 0, 0, 0};
}

// ---------------- weights: cw fp32 [oc][ic][3][3] -> Wb bf16 [r][oc][ic] --------------------
__global__ void k_wprep(const float* __restrict__ cw, bf16* __restrict__ wb) {
    int idx = blockIdx.x * 256 + threadIdx.x;
    if (idx >= 9 * OC * IC2) return;
    int r  = idx / (OC * IC2);
    int oc = (idx / IC2) & 255;
    int ic = idx & 511;
    wb[idx] = __float2bfloat16(cw[((size_t)oc * IC2 + ic) * 9 + r]);
}

// ---------------- EM A (MFMA): zt[b][k][l] = softmax_k( mu[k][:] . xt[l][:] ) ---------------
// block: 128k x 64l; wave w owns 16 l (B-frag) x all 128 k (8 A-frags)
__global__ void __launch_bounds__(256) k_z(const bf16* __restrict__ xt,
                                           const bf16* __restrict__ mub,
                                           bf16* __restrict__ zt) {
    __shared__ __align__(16) char smem[12288];
    char* tA = smem;          // mu tile 128x32 = 8KB
    char* tB = smem + 8192;   // xt tile 64x32  = 4KB
    int t = threadIdx.x, w = t >> 6, lane = t & 63;
    int b = blockIdx.y, l0 = blockIdx.x * 64;
    const bf16* Ab = mub + (size_t)b * K * C;
    const bf16* Bb = xt + ((size_t)b * L + l0) * C;
    int srow = t >> 2, sseg = t & 3, aseg = sseg ^ (srow & 3);
    char* dA0 = tA + w * 1024;
    char* dA1 = tA + 4096 + w * 1024;
    char* dB  = tB + w * 1024;
    int aoff[8], boff;
    #pragma unroll
    for (int i = 0; i < 8; i++) {
        int rowA = i * 16 + (lane & 15);
        aoff[i] = rowA * 64 + (((lane >> 4) ^ (rowA & 3)) << 4);
    }
    { int rowB = w * 16 + (lane & 15);
      boff = rowB * 64 + (((lane >> 4) ^ (rowB & 3)) << 4); }
    f32x4 acc[8];
    #pragma unroll
    for (int i = 0; i < 8; i++) acc[i] = f32x4{0.f, 0.f, 0.f, 0.f};
    for (int s = 0; s < 8; s++) {
        int cb0 = s * 32 + aseg * 8;
        __syncthreads();
        __builtin_amdgcn_global_load_lds(AS1(Ab + (size_t)srow * C + cb0),        AS3(dA0), 16, 0, 0);
        __builtin_amdgcn_global_load_lds(AS1(Ab + (size_t)(srow + 64) * C + cb0), AS3(dA1), 16, 0, 0);
        __builtin_amdgcn_global_load_lds(AS1(Bb + (size_t)srow * C + cb0),        AS3(dB),  16, 0, 0);
        __syncthreads();
        bf16x8 bfr = *(bf16x8*)(tB + boff);
        #pragma unroll
        for (int i = 0; i < 8; i++) {
            bf16x8 af = *(bf16x8*)(tA + aoff[i]);
            acc[i] = __builtin_amdgcn_mfma_f32_16x16x32_bf16(af, bfr, acc[i], 0, 0, 0);
        }
    }
    // softmax over k (i, r, quad) per column l = lane&15
    float m = -1e30f;
    #pragma unroll
    for (int i = 0; i < 8; i++)
        #pragma unroll
        for (int r = 0; r < 4; r++) m = fmaxf(m, acc[i][r]);
    m = fmaxf(m, __shfl_xor(m, 16, 64));
    m = fmaxf(m, __shfl_xor(m, 32, 64));
    float ssum = 0.f;
    #pragma unroll
    for (int i = 0; i < 8; i++)
        #pragma unroll
        for (int r = 0; r < 4; r++) { acc[i][r] = __expf(acc[i][r] - m); ssum += acc[i][r]; }
    ssum += __shfl_xor(ssum, 16, 64);
    ssum += __shfl_xor(ssum, 32, 64);
    float inv = 1.f / ssum;
    int quad = lane >> 4, col = lane & 15;
    bf16* zb = zt + (size_t)b * K * L + l0 + w * 16 + col;
    #pragma unroll
    for (int i = 0; i < 8; i++)
        #pragma unroll
        for (int r = 0; r < 4; r++) {
            int k = i * 16 + quad * 4 + r;
            zb[(size_t)k * L] = __float2bfloat16(acc[i][r] * inv);
        }
}

// ---------------- EM B (MFMA, split-K 16): part[b][ch][k][c] = sum_l zt[k][l]*x[c][l] -------
__global__ void __launch_bounds__(256) k_mu(const bf16* __restrict__ zt,
                                            const bf16* __restrict__ xb,
                                            float* __restrict__ part) {
    __shared__ __align__(16) char smem[16384];
    char* tA = smem; char* tB = smem + 8192;
    int t = threadIdx.x, w = t >> 6, lane = t & 63;
    int ct = blockIdx.x, chunk = blockIdx.y, b = blockIdx.z;   // (2,16,4)
    const bf16* Ab = zt + (size_t)b * K * L + chunk * 256;
    const bf16* Bb = xb + ((size_t)b * C + ct * 128) * L + chunk * 256;
    int srow = t >> 2, sseg = t & 3, aseg = sseg ^ (srow & 3);
    char* dA0 = tA + w * 1024; char* dA1 = tA + 4096 + w * 1024;
    char* dB0 = tB + w * 1024; char* dB1 = tB + 4096 + w * 1024;
    int wm = w >> 1, wn = w & 1;
    int aoff[4], boff[4];
    #pragma unroll
    for (int i = 0; i < 4; i++) {
        int rowA = wm * 64 + i * 16 + (lane & 15);
        aoff[i] = rowA * 64 + (((lane >> 4) ^ (rowA & 3)) << 4);
        int rowB = wn * 64 + i * 16 + (lane & 15);
        boff[i] = rowB * 64 + (((lane >> 4) ^ (rowB & 3)) << 4);
    }
    f32x4 acc[4][4];
    #pragma unroll
    for (int i = 0; i < 4; i++)
        #pragma unroll
        for (int j = 0; j < 4; j++) acc[i][j] = f32x4{0.f, 0.f, 0.f, 0.f};
    for (int s = 0; s < 8; s++) {
        int lb = s * 32 + aseg * 8;
        __syncthreads();
        __builtin_amdgcn_global_load_lds(AS1(Ab + (size_t)srow * L + lb),        AS3(dA0), 16, 0, 0);
        __builtin_amdgcn_global_load_lds(AS1(Ab + (size_t)(srow + 64) * L + lb), AS3(dA1), 16, 0, 0);
        __builtin_amdgcn_global_load_lds(AS1(Bb + (size_t)srow * L + lb),        AS3(dB0), 16, 0, 0);
        __builtin_amdgcn_global_load_lds(AS1(Bb + (size_t)(srow + 64) * L + lb), AS3(dB1), 16, 0, 0);
        __syncthreads();
        bf16x8 af[4], bfr[4];
        #pragma unroll
        for (int i = 0; i < 4; i++) af[i]  = *(bf16x8*)(tA + aoff[i]);
        #pragma unroll
        for (int j = 0; j < 4; j++) bfr[j] = *(bf16x8*)(tB + boff[j]);
        #pragma unroll
        for (int i = 0; i < 4; i++)
            #pragma unroll
            for (int j = 0; j < 4; j++)
                acc[i][j] = __builtin_amdgcn_mfma_f32_16x16x32_bf16(af[i], bfr[j], acc[i][j], 0, 0, 0);
    }
    float* pb = part + ((size_t)(b * 16 + chunk) * K) * C + ct * 128;
    int quad = lane >> 4, col = lane & 15;
    #pragma unroll
    for (int i = 0; i < 4; i++) {
        int k = wm * 64 + i * 16 + quad * 4;
        #pragma unroll
        for (int j = 0; j < 4; j++) {
            int c = wn * 64 + j * 16 + col;
            #pragma unroll
            for (int r = 0; r < 4; r++)
                pb[(size_t)(k + r) * C + c] = acc[i][j][r];
        }
    }
}

// ---------------- reduce partials + l2norm over c; emit mu_f, mu_bf [k][c], muT [c][k] ------
__global__ void k_norm(const float* __restrict__ part, float* __restrict__ mu_f,
                       bf16* __restrict__ mub, bf16* __restrict__ muT) {
    int b = blockIdx.x >> 7, k = blockIdx.x & 127, lane = threadIdx.x;  // 64 thr
    float v[4] = {0.f, 0.f, 0.f, 0.f};
    for (int ch = 0; ch < 16; ch++) {
        const float* p = part + ((size_t)(b * 16 + ch) * K + k) * C;
        #pragma unroll
        for (int j = 0; j < 4; j++) v[j] += p[lane + j * 64];
    }
    float s = v[0]*v[0] + v[1]*v[1] + v[2]*v[2] + v[3]*v[3];
    for (int o = 32; o > 0; o >>= 1) s += __shfl_xor(s, o, 64);
    float r = 1.f / (EPSV + sqrtf(s));
    float* mf = mu_f + ((size_t)b * K + k) * C;
    bf16*  mb = mub  + ((size_t)b * K + k) * C;
    bf16*  mt = muT  + (size_t)b * C * K + k;
    #pragma unroll
    for (int j = 0; j < 4; j++) {
        float val = v[j] * r;
        int c = lane + j * 64;
        mf[c] = val;
        mb[c] = __float2bfloat16(val);
        mt[(size_t)c * K] = __float2bfloat16(val);
    }
}

// ---------------- q_z (MFMA): qz[b][l'][k] = softmax_k( q[l'][:] . mu[k][:] ) ---------------
// A read straight from P2 first-half channels. block: 64l x 128k; wave owns 16 l.
__global__ void __launch_bounds__(256) k_qz(const bf16* __restrict__ P2,
                                            const bf16* __restrict__ mub,
                                            bf16* __restrict__ qz) {
    __shared__ __align__(16) char smem[12288];
    char* tA = smem;          // q tile 64x32 = 4KB
    char* tB = smem + 4096;   // mu tile 128x32 = 8KB
    int t = threadIdx.x, w = t >> 6, lane = t & 63;
    int b = blockIdx.y, tile = blockIdx.x;          // 0..255
    int n = tile >> 6, y = tile & 63;
    int img = b * NN + n;
    const bf16* Ab = P2 + ((size_t)img * PA + (size_t)(y + 1) * PW + 1) * 512;
    const bf16* Bb = mub + (size_t)b * K * C;
    int srow = t >> 2, sseg = t & 3, aseg = sseg ^ (srow & 3);
    char* dA  = tA + w * 1024;
    char* dB0 = tB + w * 1024;
    char* dB1 = tB + 4096 + w * 1024;
    int boff[8], aoff;
    #pragma unroll
    for (int j = 0; j < 8; j++) {
        int rowB = j * 16 + (lane & 15);
        boff[j] = rowB * 64 + (((lane >> 4) ^ (rowB & 3)) << 4);
    }
    { int rowA = w * 16 + (lane & 15);
      aoff = rowA * 64 + (((lane >> 4) ^ (rowA & 3)) << 4); }
    f32x4 acc[8];
    #pragma unroll
    for (int j = 0; j < 8; j++) acc[j] = f32x4{0.f, 0.f, 0.f, 0.f};
    for (int s = 0; s < 8; s++) {
        int cb0 = s * 32 + aseg * 8;
        __syncthreads();
        __builtin_amdgcn_global_load_lds(AS1(Ab + (size_t)srow * 512 + cb0),      AS3(dA),  16, 0, 0);
        __builtin_amdgcn_global_load_lds(AS1(Bb + (size_t)srow * C + cb0),        AS3(dB0), 16, 0, 0);
        __builtin_amdgcn_global_load_lds(AS1(Bb + (size_t)(srow + 64) * C + cb0), AS3(dB1), 16, 0, 0);
        __syncthreads();
        bf16x8 af = *(bf16x8*)(tA + aoff);
        #pragma unroll
        for (int j = 0; j < 8; j++) {
            bf16x8 bfr = *(bf16x8*)(tB + boff[j]);
            acc[j] = __builtin_amdgcn_mfma_f32_16x16x32_bf16(af, bfr, acc[j], 0, 0, 0);
        }
    }
    // softmax over k (j, 16-lane group) per row r; store [l][k]
    int quad = lane >> 4, col = lane & 15;
    bf16* qb = qz + ((size_t)b * NL + n * L + y * WW + w * 16 + quad * 4) * K;
    #pragma unroll
    for (int r = 0; r < 4; r++) {
        float mm = acc[0][r];
        #pragma unroll
        for (int j = 1; j < 8; j++) mm = fmaxf(mm, acc[j][r]);
        mm = fmaxf(mm, __shfl_xor(mm, 1, 64));
        mm = fmaxf(mm, __shfl_xor(mm, 2, 64));
        mm = fmaxf(mm, __shfl_xor(mm, 4, 64));
        mm = fmaxf(mm, __shfl_xor(mm, 8, 64));
        float ss = 0.f;
        float e[8];
        #pragma unroll
        for (int j = 0; j < 8; j++) { e[j] = __expf(acc[j][r] - mm); ss += e[j]; }
        ss += __shfl_xor(ss, 1, 64);
        ss += __shfl_xor(ss, 2, 64);
        ss += __shfl_xor(ss, 4, 64);
        ss += __shfl_xor(ss, 8, 64);
        float inv = 1.f / ss;
        #pragma unroll
        for (int j = 0; j < 8; j++)
            qb[(size_t)r * K + j * 16 + col] = __float2bfloat16(e[j] * inv);
    }
}

// ---------------- rec (MFMA): P2 ch256+ [l'][c] = sum_k qz[l'][k] * muT[c][k] ---------------
__global__ void __launch_bounds__(256) k_rec(const bf16* __restrict__ qz,
                                             const bf16* __restrict__ muT,
                                             bf16* __restrict__ P2) {
    __shared__ __align__(16) char smem[16384];
    char* tA = smem; char* tB = smem + 8192;
    int t = threadIdx.x, w = t >> 6, lane = t & 63;
    int ct = blockIdx.x, lt = blockIdx.y, b = blockIdx.z;   // (2,128,4)
    const bf16* Ab = qz + ((size_t)b * NL + lt * 128) * K;
    const bf16* Bb = muT + ((size_t)b * C + ct * 128) * K;
    int srow = t >> 2, sseg = t & 3, aseg = sseg ^ (srow & 3);
    char* dA0 = tA + w * 1024; char* dA1 = tA + 4096 + w * 1024;
    char* dB0 = tB + w * 1024; char* dB1 = tB + 4096 + w * 1024;
    int wm = w >> 1, wn = w & 1;
    int aoff[4], boff[4];
    #pragma unroll
    for (int i = 0; i < 4; i++) {
        int rowA = wm * 64 + i * 16 + (lane & 15);
        aoff[i] = rowA * 64 + (((lane >> 4) ^ (rowA & 3)) << 4);
        int rowB = wn * 64 + i * 16 + (lane & 15);
        boff[i] = rowB * 64 + (((lane >> 4) ^ (rowB & 3)) << 4);
    }
    f32x4 acc[4][4];
    #pragma unroll
    for (int i = 0; i < 4; i++)
        #pragma unroll
        for (int j = 0; j < 4; j++) acc[i][j] = f32x4{0.f, 0.f, 0.f, 0.f};
    for (int s = 0; s < 4; s++) {
        int kb = s * 32 + aseg * 8;
        __syncthreads();
        __builtin_amdgcn_global_load_lds(AS1(Ab + (size_t)srow * K + kb),        AS3(dA0), 16, 0, 0);
        __builtin_amdgcn_global_load_lds(AS1(Ab + (size_t)(srow + 64) * K + kb), AS3(dA1), 16, 0, 0);
        __builtin_amdgcn_global_load_lds(AS1(Bb + (size_t)srow * K + kb),        AS3(dB0), 16, 0, 0);
        __builtin_amdgcn_global_load_lds(AS1(Bb + (size_t)(srow + 64) * K + kb), AS3(dB1), 16, 0, 0);
        __syncthreads();
        bf16x8 af[4], bfr[4];
        #pragma unroll
        for (int i = 0; i < 4; i++) af[i]  = *(bf16x8*)(tA + aoff[i]);
        #pragma unroll
        for (int j = 0; j < 4; j++) bfr[j] = *(bf16x8*)(tB + boff[j]);
        #pragma unroll
        for (int i = 0; i < 4; i++)
            #pragma unroll
            for (int j = 0; j < 4; j++)
                acc[i][j] = __builtin_amdgcn_mfma_f32_16x16x32_bf16(af[i], bfr[j], acc[i][j], 0, 0, 0);
    }
    int quad = lane >> 4, col = lane & 15;
    #pragma unroll
    for (int i = 0; i < 4; i++) {
        int lbase = lt * 128 + wm * 64 + i * 16 + quad * 4;
        #pragma unroll
        for (int r = 0; r < 4; r++) {
            int l = lbase + r;
            int n = l >> 12, p = l & 4095;
            int y = p >> 6, xp = p & 63;
            bf16* dst = P2 + ((size_t)(b * NN + n) * PA + (size_t)(y + 1) * PW + xp + 1) * 512 + 256;
            #pragma unroll
            for (int j = 0; j < 4; j++)
                dst[ct * 128 + wn * 64 + j * 16 + col] = __float2bfloat16(acc[i][j][r]);
        }
    }
}

// ---------------- MFMA implicit-GEMM conv (unchanged from R3) -------------------------------
__global__ void __launch_bounds__(256) k_conv(const bf16* __restrict__ P2,
                                              const bf16* __restrict__ Wb,
                                              const float* __restrict__ cb,
                                              float* __restrict__ out) {
    __shared__ __align__(16) char smem[16384];
    char* tA = smem;
    char* tB = smem + 8192;
    int t = threadIdx.x, wave = t >> 6, lane = t & 63;
    int m0  = blockIdx.x * 128;
    int y0  = blockIdx.y * 2;
    int img = blockIdx.z;

    int px0  = t >> 2;
    int sseg = t & 3;
    int aseg = sseg ^ (px0 & 3);
    int px1  = px0 + 64;
    size_t baseB0 = ((size_t)img * PA + (size_t)(y0 + (px0 >> 6)) * PW + (px0 & 63)) * 512 + aseg * 8;
    size_t baseB1 = ((size_t)img * PA + (size_t)(y0 + (px1 >> 6)) * PW + (px1 & 63)) * 512 + aseg * 8;
    size_t baseA0 = (size_t)(m0 + px0) * 512 + aseg * 8;
    size_t baseA1 = (size_t)(m0 + px1) * 512 + aseg * 8;
    char* ldsA0 = tA + wave * 1024;  char* ldsA1 = tA + 4096 + wave * 1024;
    char* ldsB0 = tB + wave * 1024;  char* ldsB1 = tB + 4096 + wave * 1024;

    int wm = wave >> 1, wn = wave & 1;
    int aoff[4], boff[4];
    #pragma unroll
    for (int i = 0; i < 4; i++) {
        int rowA = wm * 64 + i * 16 + (lane & 15);
        aoff[i] = (rowA * 4 + ((lane >> 4) ^ (rowA & 3))) * 16;
        int rowB = wn * 64 + i * 16 + (lane & 15);
        boff[i] = (rowB * 4 + ((lane >> 4) ^ (rowB & 3))) * 16;
    }

    f32x4 acc[4][4];
    #pragma unroll
    for (int i = 0; i < 4; i++) {
        int oc = m0 + wm * 64 + i * 16 + (lane >> 4) * 4;
        #pragma unroll
        for (int r = 0; r < 4; r++) {
            float bv = cb[oc + r];
            #pragma unroll
            for (int j = 0; j < 4; j++) acc[i][j][r] = bv;
        }
    }

    for (int kk = 0; kk < 144; kk++) {
        int r   = kk >> 4;
        int ic0 = (kk & 15) << 5;
        size_t offB = (size_t)((r / 3) * PW + (r % 3)) * 512 + ic0;
        size_t offA = (size_t)r * (OC * IC2) + ic0;
        __syncthreads();
        __builtin_amdgcn_global_load_lds(AS1(Wb + baseA0 + offA), AS3(ldsA0), 16, 0, 0);
        __builtin_amdgcn_global_load_lds(AS1(Wb + baseA1 + offA), AS3(ldsA1), 16, 0, 0);
        __builtin_amdgcn_global_load_lds(AS1(P2 + baseB0 + offB), AS3(ldsB0), 16, 0, 0);
        __builtin_amdgcn_global_load_lds(AS1(P2 + baseB1 + offB), AS3(ldsB1), 16, 0, 0);
        __syncthreads();
        bf16x8 af[4], bfr[4];
        #pragma unroll
        for (int i = 0; i < 4; i++) af[i]  = *(bf16x8*)(tA + aoff[i]);
        #pragma unroll
        for (int j = 0; j < 4; j++) bfr[j] = *(bf16x8*)(tB + boff[j]);
        #pragma unroll
        for (int i = 0; i < 4; i++)
            #pragma unroll
            for (int j = 0; j < 4; j++)
                acc[i][j] = __builtin_amdgcn_mfma_f32_16x16x32_bf16(af[i], bfr[j], acc[i][j], 0, 0, 0);
    }

    int pxbase = blockIdx.y * 128 + wn * 64 + (lane & 15);
    #pragma unroll
    for (int i = 0; i < 4; i++) {
        int oc = m0 + wm * 64 + i * 16 + (lane >> 4) * 4;
        #pragma unroll
        for (int j = 0; j < 4; j++) {
            int px = pxbase + j * 16;
            #pragma unroll
            for (int r = 0; r < 4; r++)
                out[((size_t)img * OC + oc + r) * L + px] = acc[i][j][r];
        }
    }
}

// ---------------- mu_f [b][k][c] -> out tail [b][c][k] fp32 ---------------------------------
__global__ void k_muout(const float* __restrict__ mu_f, float* __restrict__ out) {
    int i = blockIdx.x * 256 + threadIdx.x;       // over 131072, out index (b,c,k)
    int b = i >> 15, rem = i & 32767;
    int c = rem >> 7, k = rem & 127;
    out[(size_t)16777216 + i] = mu_f[((size_t)b * K + k) * C + c];
}

extern "C" void kernel_launch(void* const* d_in, const int* in_sizes, int n_in,
                              void* d_out, int out_size, void* d_ws, size_t ws_size,
                              hipStream_t stream) {
    const float* x   = (const float*)d_in[0];   // [4][256][4096]
    const float* qy  = (const float*)d_in[1];   // [16][256][4096]
    const float* mu0 = (const float*)d_in[2];   // [256][128]
    const float* cw  = (const float*)d_in[3];   // [256][512][3][3]
    const float* cb  = (const float*)d_in[4];   // [256]
    float* out = (float*)d_out;

    // workspace layout (bytes), total 91.6 MB:
    //   mu_f   @ 0         (512 KB fp32 [b][k][c])
    //   mu_bf  @ 524288    (256 KB bf16 [b][k][c])
    //   muT_bf @ 786432    (256 KB bf16 [b][c][k])
    //   Wb     @ 1048576   (2.25 MB bf16 [9][oc][ic])
    //   zt/qz  @ 3407872   (16.78 MB: EM zt bf16 [b][k][l] 4.19MB, later qz bf16 [b][l'][k])
    //   P2     @ 20185088  (71.37 MB bf16 [16][66*66][512])
    //     EM-lifetime overlays inside P2: x_bf @+0 (8.39MB), part @+8388608 (8.39MB fp32),
    //     xt @+16777216 (8.39MB) — all dead before P2 is first written (after EM).
    char* ws = (char*)d_ws;
    float* mu_f = (float*)(ws);
    bf16*  mu_b = (bf16*) (ws + 524288);
    bf16*  muT  = (bf16*) (ws + 786432);
    bf16*  Wb   = (bf16*) (ws + 1048576);
    bf16*  zt   = (bf16*) (ws + 3407872);
    bf16*  qz   = (bf16*) (ws + 3407872);
    bf16*  P2   = (bf16*) (ws + 20185088);
    bf16*  x_bf = (bf16*) (ws + 20185088);
    float* part = (float*)(ws + 20185088 + 8388608);
    bf16*  xt   = (bf16*) (ws + 20185088 + 16777216);

    k_init<<<512, 256, 0, stream>>>(mu0, mu_f, mu_b);
    k_prepx<<<dim3(64, 4, 4), 256, 0, stream>>>(x, x_bf, xt);

    for (int it = 0; it < 5; it++) {
        k_z<<<dim3(64, 4), 256, 0, stream>>>(xt, mu_b, zt);
        k_mu<<<dim3(2, 16, 4), 256, 0, stream>>>(zt, x_bf, part);
        k_norm<<<512, 64, 0, stream>>>(part, mu_f, mu_b, muT);
    }

    k_prepq<<<dim3(64, 4, 16), 256, 0, stream>>>(qy, P2);
    k_zborder<<<dim3(260, 16), 64, 0, stream>>>((uint4*)P2);
    k_wprep<<<4608, 256, 0, stream>>>(cw, Wb);

    k_qz<<<dim3(256, 4), 256, 0, stream>>>(P2, mu_b, qz);
    k_rec<<<dim3(2, 128, 4), 256, 0, stream>>>(qz, muT, P2);
    k_conv<<<dim3(2, 32, 16), 256, 0, stream>>>(P2, Wb, cb, out);
    k_muout<<<512, 256, 0, stream>>>(mu_f, out);
}